// Round 3
// baseline (159.109 us; speedup 1.0000x reference)
//
#include <hip/hip_runtime.h>
#include <hip/hip_bf16.h>

// Flash attention fwd, B=2 H=16 S=2048 D=64, fp32 in/out, bf16 MFMA compute.
// R13: R12's 32x32x16 MFMA + fully in-register P transform, but the
// lane<->lane^32 exchange uses __shfl_xor(.,32) + cndmask selects instead of
// v_permlane32_swap_b32 (R12 FAILED, absmax 0.18: every other layout fact is
// verified by R11 passing or guide m74/m101; the swap direction is the one
// unexecuted primitive -- this round pins it with known-semantics shuffles).
//   QK with 32x32x16: C layout row(kv)=(r&3)+8*(r>>2)+4*hi, col(q)=lane&31.
//   Lane l / l^32 jointly hold each 16-wide kv slice; PV B-operand word w
//   needs: hi=0: [own p0p1, own p2p3, partner p0p1, partner p2p3] (kv 0..7)
//          hi=1: [partner p4p5, partner p6p7, own p4p5, own p6p7] (kv 8..15)
//   -> f = shfl_xor(hi ? x : y, 32) delivers exactly the foreign word for
//      both roles; cndmask routes own/foreign into w0..w3.
// LDS epilogue-only. Barrier-free K-loop, K-register double-buffer,
// scale-folded-into-Q softmax (R11-verified). Prepack identical to R12.
// Verified MFMA conventions (learn_hip m74/m101; R2-R11 HW-validated):
//   MFMA(A,B,C): C[i][j] = sum_k A[i][k]*B^T[j][k]
//   32x32 A/B: elem[i or j = lane&31][k = (lane>>5)*8 + jj]
//   32x32 C:   col(j)=lane&31, row(i)=(reg&3)+8*(reg>>2)+4*(lane>>5)

typedef __attribute__((ext_vector_type(8))) short short8;
typedef __attribute__((ext_vector_type(16))) float floatx16;

#define SS 2048
#define DD 64
#define NITER (SS / 64)     // 64 kv rows per block-iteration
#define LOG2E 1.44269504f

#define MFMA32(a, b, c) __builtin_amdgcn_mfma_f32_32x32x16_bf16(a, b, c, 0, 0, 0)

// K-frag pool: 32 heads * 64 kvb * 4 ks * 64 lanes * 8 shorts = 8 MB
#define KF_SHORTS (32 * 64 * 4 * 64 * 8)
// V-frag pool: 32 heads * 64 kvb * (2 dt * 2 ksl) * 64 lanes * 8 shorts = 8 MB
#define VF_SHORTS (32 * 64 * 4 * 64 * 8)

// two f32 -> packed bf16x2 (half-up rounding; proven R8-R11)
static __device__ inline unsigned pack2bf(float a, float b) {
    unsigned ua = __builtin_bit_cast(unsigned, a) + 0x8000u;
    unsigned ub = __builtin_bit_cast(unsigned, b) + 0x8000u;
    return __builtin_amdgcn_perm(ub, ua, 0x07060302u);
}

// two f32 -> packed bf16x2 in ONE instruction (RNE; proven R11), low<-lo hi<-hi
static __device__ inline unsigned cvtpk(float lo, float hi) {
    unsigned r;
    asm("v_cvt_pk_bf16_f32 %0, %1, %2" : "=v"(r) : "v"(lo), "v"(hi));
    return r;
}

// ---------------- pre-pass: frag-major bf16 K and V^T for 32x32 MFMA --------
__global__ __launch_bounds__(256)
void prepack_kernel(const float* __restrict__ K, const float* __restrict__ V,
                    short* __restrict__ Kf, short* __restrict__ Vf)
{
    int t = blockIdx.x * 256 + threadIdx.x;     // [0, 1048576)
    int lane = t & 63;
    int l31 = lane & 31, hi = lane >> 5;
    if (t < 524288) {
        // K A-frag chunk: c = (hd*64 + kvb)*4 + ks
        // lane holds K[kvb*32 + l31][ks*16 + hi*8 + jj], jj=0..7
        int c = t >> 6;
        int ks = c & 3, kvb = (c >> 2) & 63, hd = c >> 8;
        const float* src = K + (size_t)hd * 131072
                             + (size_t)(kvb * 32 + l31) * 64 + ks * 16 + hi * 8;
        float4 f0 = *(const float4*)src;
        float4 f1 = *(const float4*)(src + 4);
        uint4 o;
        o.x = pack2bf(f0.x, f0.y); o.y = pack2bf(f0.z, f0.w);
        o.z = pack2bf(f1.x, f1.y); o.w = pack2bf(f1.z, f1.w);
        *(uint4*)(Kf + (size_t)t * 8) = o;
    } else {
        // V^T A-frag chunk: c = ((hd*64 + kvb)*2 + dt)*2 + ksl
        // lane holds V[kvb*32 + ksl*16 + hi*8 + jj][dt*32 + l31], jj=0..7
        int u = t - 524288;
        int c = u >> 6;
        int ksl = c & 1, dt = (c >> 1) & 1, kvb = (c >> 2) & 63, hd = c >> 8;
        const float* src = V + (size_t)hd * 131072
                             + (size_t)(kvb * 32 + ksl * 16 + hi * 8) * 64
                             + dt * 32 + l31;
        float v[8];
#pragma unroll
        for (int jj = 0; jj < 8; ++jj) v[jj] = src[(size_t)jj * 64];
        uint4 o;
        o.x = pack2bf(v[0], v[1]); o.y = pack2bf(v[2], v[3]);
        o.z = pack2bf(v[4], v[5]); o.w = pack2bf(v[6], v[7]);
        *(uint4*)(Vf + (size_t)u * 8) = o;
    }
}

// ---------------- attention kernel ----------------
__global__ __launch_bounds__(256, 4)
void fattn_kernel(const float* __restrict__ Q, const short* __restrict__ Kf,
                  const short* __restrict__ Vf, const float* __restrict__ isf,
                  float* __restrict__ O)
{
    // LDS: epilogue-only (cross-w_n O/l exchange). No P buffer.
    __shared__ __align__(16) char smem[17664];
    float* O_buf = (float*)smem;               // [64][68] f32, 17408 B
    float* l_buf = (float*)(smem + 17408);     // 256 B
#define OSTR 68

    const int tid  = threadIdx.x;
    const int wave = tid >> 6;
    const int w_m  = wave & 1;     // q half (32 rows)
    const int w_n  = wave >> 1;    // kv half (32 rows per iter)
    const int lane = tid & 63;
    const int l31  = lane & 31;
    const int hi   = lane >> 5;

    const int b    = blockIdx.x & 1023;
    const int xcd  = b & 7;
    const int j    = b >> 3;
    const int head = xcd + 8 * (j & 3);  // 0..31
    const int qt   = j >> 2;             // 0..31

    const float scl2 = (1.0f / isf[0]) * LOG2E;   // folded into Q fragments

    const float* Qh = Q + (size_t)head * SS * DD;
    float*       Oh = O + (size_t)head * SS * DD;

    // frag-major base pointers; advance 8192 shorts per double-iter
    const short* kp = Kf + (size_t)head * 131072 + w_n * 2048 + lane * 8;
    const short* vp = Vf + (size_t)head * 131072 + w_n * 2048 + lane * 8;

    // ---- K tile 0 into buffer A (latency covered by Q pack below) ----
    short8 kA0 = *(const short8*)(kp + 0);
    short8 kA1 = *(const short8*)(kp + 512);
    short8 kA2 = *(const short8*)(kp + 1024);
    short8 kA3 = *(const short8*)(kp + 1536);
    short8 kB0, kB1, kB2, kB3;

    // ---- Q fragments (B-operand), pre-scaled by scl2 ----
    // B^T[j=q=l31][k = ks*16 + hi*8 + jj]
    short8 q_frag[4];
    {
        const float* qrow = Qh + (size_t)(qt * 64 + w_m * 32 + l31) * DD;
#pragma unroll
        for (int ks = 0; ks < 4; ++ks) {
            float4 f0 = *(const float4*)(qrow + ks * 16 + hi * 8);
            float4 f1 = *(const float4*)(qrow + ks * 16 + hi * 8 + 4);
            uint4 qp;
            qp.x = pack2bf(f0.x * scl2, f0.y * scl2);
            qp.y = pack2bf(f0.z * scl2, f0.w * scl2);
            qp.z = pack2bf(f1.x * scl2, f1.y * scl2);
            qp.w = pack2bf(f1.z * scl2, f1.w * scl2);
            q_frag[ks] = __builtin_bit_cast(short8, qp);
        }
    }

    floatx16 o_acc[2];   // [dt], C[i=d=dt*32+crow][j=q]
#pragma unroll
    for (int i = 0; i < 16; ++i) { o_acc[0][i] = 0.0f; o_acc[1][i] = 0.0f; }
    float lsum = 0.0f;   // q=l31, this lane's 16 kv per tile

// one 32q x 32kv tile: QK (K frags resident), exp2, in-register P transform
// (cvtpk + shfl_xor(32) + cndmask), PV. Zero LDS ops in the loop.
#define FBODY(K0, K1, K2, K3, V00, V01, V10, V11)                          \
    do {                                                                   \
        floatx16 s = {0.f,0.f,0.f,0.f,0.f,0.f,0.f,0.f,                     \
                      0.f,0.f,0.f,0.f,0.f,0.f,0.f,0.f};                    \
        s = MFMA32(K0, q_frag[0], s);                                      \
        s = MFMA32(K1, q_frag[1], s);                                      \
        s = MFMA32(K2, q_frag[2], s);                                      \
        s = MFMA32(K3, q_frag[3], s);                                      \
        float p[16];                                                       \
        _Pragma("unroll")                                                  \
        for (int i = 0; i < 16; ++i) p[i] = __builtin_amdgcn_exp2f(s[i]);  \
        lsum += (((p[0]+p[1])+(p[2]+p[3]))+((p[4]+p[5])+(p[6]+p[7])))      \
              + (((p[8]+p[9])+(p[10]+p[11]))+((p[12]+p[13])+(p[14]+p[15])));\
        /* lane (q,hi): p[r] holds kv=(r&3)+8*(r>>2)+4*hi of this 32-kv */ \
        unsigned x0 = cvtpk(p[0], p[1]),   x1 = cvtpk(p[2], p[3]);         \
        unsigned y0 = cvtpk(p[4], p[5]),   y1 = cvtpk(p[6], p[7]);         \
        unsigned x2 = cvtpk(p[8], p[9]),   x3 = cvtpk(p[10], p[11]);       \
        unsigned y2 = cvtpk(p[12], p[13]), y3 = cvtpk(p[14], p[15]);       \
        /* foreign words: hi=0 gets partner x (kv 4..7 / 20..23),          \
           hi=1 gets partner y (kv 8..11 / 24..27) */                      \
        unsigned f0 = __shfl_xor(hi ? x0 : y0, 32);                        \
        unsigned f1 = __shfl_xor(hi ? x1 : y1, 32);                        \
        unsigned f2 = __shfl_xor(hi ? x2 : y2, 32);                        \
        unsigned f3 = __shfl_xor(hi ? x3 : y3, 32);                        \
        uint4 B0u = { hi ? f0 : x0, hi ? f1 : x1,                          \
                      hi ? y0 : f0, hi ? y1 : f1 };  /* kv 0..15 slice */  \
        uint4 B1u = { hi ? f2 : x2, hi ? f3 : x3,                          \
                      hi ? y2 : f2, hi ? y3 : f3 };  /* kv 16..31 slice */ \
        short8 Bf0 = __builtin_bit_cast(short8, B0u);                      \
        short8 Bf1 = __builtin_bit_cast(short8, B1u);                      \
        o_acc[0] = MFMA32(V00, Bf0, o_acc[0]);                             \
        o_acc[1] = MFMA32(V10, Bf0, o_acc[1]);                             \
        o_acc[0] = MFMA32(V01, Bf1, o_acc[0]);                             \
        o_acc[1] = MFMA32(V11, Bf1, o_acc[1]);                             \
    } while (0)

    // ---------------- barrier-free, K-double-buffered K-loop ----------------
    for (int kb = 0; kb < NITER; kb += 2) {
        // even tile kb: V (this tile) + K prefetch (tile kb+1) issued first
        short8 v00 = *(const short8*)(vp + 0);
        short8 v01 = *(const short8*)(vp + 512);
        short8 v10 = *(const short8*)(vp + 1024);
        short8 v11 = *(const short8*)(vp + 1536);
        kB0 = *(const short8*)(kp + 4096);
        kB1 = *(const short8*)(kp + 4608);
        kB2 = *(const short8*)(kp + 5120);
        kB3 = *(const short8*)(kp + 5632);
        FBODY(kA0, kA1, kA2, kA3, v00, v01, v10, v11);

        // odd tile kb+1: V (tile kb+1) + K prefetch (tile kb+2 -> buffer A).
        // Tail prefetch overruns into the next head's Kf / the Vf pool --
        // valid d_ws memory, result unused (same guarantee as R10-R12).
        short8 w00 = *(const short8*)(vp + 4096);
        short8 w01 = *(const short8*)(vp + 4608);
        short8 w10 = *(const short8*)(vp + 5120);
        short8 w11 = *(const short8*)(vp + 5632);
        kA0 = *(const short8*)(kp + 8192);
        kA1 = *(const short8*)(kp + 8704);
        kA2 = *(const short8*)(kp + 9216);
        kA3 = *(const short8*)(kp + 9728);
        FBODY(kB0, kB1, kB2, kB3, w00, w01, w10, w11);

        kp += 8192; vp += 8192;
    }

    // ---- epilogue ----
    // lane (q,hi) covers 16 of its wave's 32 kv; partner l^32 has the rest.
    lsum += __shfl_xor(lsum, 32);

    // cross-w_n exchange: w_n=1 stores partial O + l, w_n=0 combines.
    const int row = w_m * 32 + l31;
    if (w_n == 1) {
#pragma unroll
        for (int dt = 0; dt < 2; ++dt)
#pragma unroll
            for (int g = 0; g < 4; ++g) {
                float4 v = { o_acc[dt][g * 4 + 0], o_acc[dt][g * 4 + 1],
                             o_acc[dt][g * 4 + 2], o_acc[dt][g * 4 + 3] };
                *(float4*)&O_buf[row * OSTR + dt * 32 + g * 8 + hi * 4] = v;
            }
        if (lane < 32) l_buf[row] = lsum;
    }
    __syncthreads();
    if (w_n == 0) {
        float lt = lsum + l_buf[row];
        float rl = 1.0f / lt;
        float* orow = Oh + (size_t)(qt * 64 + row) * DD;
#pragma unroll
        for (int dt = 0; dt < 2; ++dt)
#pragma unroll
            for (int g = 0; g < 4; ++g) {
                float4 part = *(float4*)&O_buf[row * OSTR + dt * 32 + g * 8 + hi * 4];
                float4 v;
                v.x = (o_acc[dt][g * 4 + 0] + part.x) * rl;
                v.y = (o_acc[dt][g * 4 + 1] + part.y) * rl;
                v.z = (o_acc[dt][g * 4 + 2] + part.z) * rl;
                v.w = (o_acc[dt][g * 4 + 3] + part.w) * rl;
                *(float4*)(orow + dt * 32 + g * 8 + hi * 4) = v;
            }
    }
}

extern "C" void kernel_launch(void* const* d_in, const int* in_sizes, int n_in,
                              void* d_out, int out_size, void* d_ws, size_t ws_size,
                              hipStream_t stream) {
    const float* Q   = (const float*)d_in[0];
    const float* K   = (const float*)d_in[1];
    const float* V   = (const float*)d_in[2];
    const float* isf = (const float*)d_in[3];
    float* O = (float*)d_out;

    short* Kf = (short*)d_ws;                 // 8 MB
    short* Vf = Kf + KF_SHORTS;               // 8 MB  (total 16 MB of d_ws)

    prepack_kernel<<<4096, 256, 0, stream>>>(K, V, Kf, Vf);
    fattn_kernel<<<1024, 256, 0, stream>>>(Q, Kf, Vf, isf, O);
}